// Round 1
// baseline (1796.936 us; speedup 1.0000x reference)
//
#include <hip/hip_runtime.h>
#include <math.h>

#define CDIM 256
#define LDIM 16384
#define NH 8
#define HD 32
#define FFN 512
#define RB 32              // rows per block in main kernel
#define CHUNKS (LDIM/RB)   // 512
#define EPS 1e-5f
#define SCALE 0.17677669529663687f  // 1/sqrt(32)

// ---------------- helpers ----------------

__device__ inline float wave_reduce_sum64(float v) {
#pragma unroll
    for (int m = 32; m >= 1; m >>= 1) v += __shfl_xor(v, m, 64);
    return v;
}

// GEMM tile: smDst[r][c] = (RELU? relu : id)(smSrc[r][:] @ W[:, colOff+c] + bias[c])
// Thread mapping: rg = (lane>>4) picks 8 rows, c0 = 4*(wave*16 + (lane&15)) picks 4 cols.
template <bool RELU>
__device__ inline void tile_gemm(const float* __restrict__ smSrc, float* __restrict__ smDst,
                                 const float* __restrict__ W, int ldw, int colOff,
                                 const float* __restrict__ bias,  // already offset so bias[c0] is right
                                 int rg, int c0) {
    float4 acc[8];
#pragma unroll
    for (int r = 0; r < 8; ++r) acc[r] = make_float4(0.f, 0.f, 0.f, 0.f);

    for (int k = 0; k < CDIM; k += 4) {
        const float* wp = W + (size_t)k * ldw + colOff + c0;
        float4 w0 = *(const float4*)(wp);
        float4 w1 = *(const float4*)(wp + ldw);
        float4 w2 = *(const float4*)(wp + 2 * ldw);
        float4 w3 = *(const float4*)(wp + 3 * ldw);
#pragma unroll
        for (int r = 0; r < 8; ++r) {
            float4 a = *(const float4*)&smSrc[(8 * rg + r) * CDIM + k];
            acc[r].x = fmaf(a.x, w0.x, fmaf(a.y, w1.x, fmaf(a.z, w2.x, fmaf(a.w, w3.x, acc[r].x))));
            acc[r].y = fmaf(a.x, w0.y, fmaf(a.y, w1.y, fmaf(a.z, w2.y, fmaf(a.w, w3.y, acc[r].y))));
            acc[r].z = fmaf(a.x, w0.z, fmaf(a.y, w1.z, fmaf(a.z, w2.z, fmaf(a.w, w3.z, acc[r].z))));
            acc[r].w = fmaf(a.x, w0.w, fmaf(a.y, w1.w, fmaf(a.z, w2.w, fmaf(a.w, w3.w, acc[r].w))));
        }
    }
    float4 bb = *(const float4*)&bias[c0];
#pragma unroll
    for (int r = 0; r < 8; ++r) {
        float4 t;
        t.x = acc[r].x + bb.x;
        t.y = acc[r].y + bb.y;
        t.z = acc[r].z + bb.z;
        t.w = acc[r].w + bb.w;
        if (RELU) {
            t.x = fmaxf(t.x, 0.f); t.y = fmaxf(t.y, 0.f);
            t.z = fmaxf(t.z, 0.f); t.w = fmaxf(t.w, 0.f);
        }
        *(float4*)&smDst[(8 * rg + r) * CDIM + c0] = t;
    }
}

// ---------------- kernel 1: q = ln(query) @ W_q + b_q, scaled ----------------

__global__ __launch_bounds__(256) void qprep_kernel(const float* __restrict__ query,
                                                    const float* __restrict__ Wq,
                                                    const float* __restrict__ bq,
                                                    const float* __restrict__ gq,
                                                    const float* __restrict__ beq,
                                                    float* __restrict__ qs) {
    int b = blockIdx.x;
    int tid = threadIdx.x;
    int wave = tid >> 6, lane = tid & 63;
    __shared__ float sh[CDIM];
    __shared__ float red[8];

    float x = query[b * CDIM + tid];
    float s = x, sq = x * x;
#pragma unroll
    for (int m = 32; m >= 1; m >>= 1) { s += __shfl_xor(s, m, 64); sq += __shfl_xor(sq, m, 64); }
    if (lane == 0) { red[wave] = s; red[4 + wave] = sq; }
    __syncthreads();
    float ts = red[0] + red[1] + red[2] + red[3];
    float tq = red[4] + red[5] + red[6] + red[7];
    float mean = ts * (1.f / CDIM);
    float var = tq * (1.f / CDIM) - mean * mean;
    float rstd = rsqrtf(var + EPS);
    sh[tid] = (x - mean) * rstd * gq[tid] + beq[tid];
    __syncthreads();

    float acc = bq[tid];
    for (int k = 0; k < CDIM; ++k) acc = fmaf(sh[k], Wq[k * CDIM + tid], acc);
    qs[b * CDIM + tid] = acc * SCALE;
}

// ---------------- kernel 2: fused mem pipeline + attention partials ----------------

__global__ __launch_bounds__(256, 2) void main_kernel(const float* __restrict__ mem,
                                                      const float* __restrict__ Wip,
                                                      const float* __restrict__ bip,
                                                      const float* __restrict__ gip,
                                                      const float* __restrict__ beip,
                                                      const float* __restrict__ Wkv,
                                                      const float* __restrict__ bkv,
                                                      const float* __restrict__ ior,
                                                      const float* __restrict__ qs,
                                                      float* __restrict__ partials) {
    int blk = blockIdx.x;
    int b = blk / CHUNKS;
    int chunk = blk % CHUNKS;
    int row0 = chunk * RB;
    int tid = threadIdx.x;
    int wave = tid >> 6, lane = tid & 63;
    int rg = lane >> 4;
    int cl = lane & 15;
    int c0 = 4 * (wave * 16 + cl);

    __shared__ float smA[RB * CDIM];  // mem rows -> K -> V
    __shared__ float smM[RB * CDIM];  // m = ln(relu(mem@Wip+b))

    // stage mem rows (32 KiB contiguous, coalesced float4)
    {
        const float4* src = (const float4*)(mem + ((size_t)b * LDIM + row0) * CDIM);
        float4* dst = (float4*)smA;
        for (int i = tid; i < RB * CDIM / 4; i += 256) dst[i] = src[i];
    }
    __syncthreads();

    // GEMM1 + bias + relu -> smM
    tile_gemm<true>(smA, smM, Wip, CDIM, 0, bip, rg, c0);
    __syncthreads();

    // LayerNorm each row of smM (wave w handles rows 8w..8w+7)
    {
#pragma unroll
        for (int rr = 0; rr < 8; ++rr) {
            int r = 8 * wave + rr;
            float4 x = *(const float4*)&smM[r * CDIM + 4 * lane];
            float s = x.x + x.y + x.z + x.w;
            float sq = x.x * x.x + x.y * x.y + x.z * x.z + x.w * x.w;
#pragma unroll
            for (int m = 32; m >= 1; m >>= 1) { s += __shfl_xor(s, m, 64); sq += __shfl_xor(sq, m, 64); }
            float mean = s * (1.f / CDIM);
            float var = sq * (1.f / CDIM) - mean * mean;
            float rstd = rsqrtf(var + EPS);
            float4 g = *(const float4*)&gip[4 * lane];
            float4 be = *(const float4*)&beip[4 * lane];
            float4 y;
            y.x = (x.x - mean) * rstd * g.x + be.x;
            y.y = (x.y - mean) * rstd * g.y + be.y;
            y.z = (x.z - mean) * rstd * g.z + be.z;
            y.w = (x.w - mean) * rstd * g.w + be.w;
            *(float4*)&smM[r * CDIM + 4 * lane] = y;
        }
    }
    __syncthreads();

    // K = m @ Wkv[:, :C] + bkv[:C] -> smA (overwrite mem rows)
    tile_gemm<false>(smM, smA, Wkv, 2 * CDIM, 0, bkv, rg, c0);
    __syncthreads();

    // scores: thread (h = tid>>5, d = tid&31); each holds s[r] for all 32 rows of its head
    int h = tid >> 5;
    int d = tid & 31;
    float qv = qs[b * CDIM + h * HD + d];
    const float* iorp = ior + ((size_t)b * NH + h) * LDIM + row0;
    float sarr[RB];
#pragma unroll
    for (int r = 0; r < RB; ++r) {
        float p = qv * smA[r * CDIM + h * HD + d];
#pragma unroll
        for (int m = 16; m >= 1; m >>= 1) p += __shfl_xor(p, m, 64);  // sum over d within 32-lane half
        sarr[r] = p * iorp[r];
    }
    float M = -1e30f;
#pragma unroll
    for (int r = 0; r < RB; ++r) M = fmaxf(M, sarr[r]);
    float S = 0.f;
#pragma unroll
    for (int r = 0; r < RB; ++r) { sarr[r] = expf(sarr[r] - M); S += sarr[r]; }
    __syncthreads();

    // V = m @ Wkv[:, C:] + bkv[C:] -> smA (overwrite K)
    tile_gemm<false>(smM, smA, Wkv, 2 * CDIM, CDIM, bkv + CDIM, rg, c0);
    __syncthreads();

    // O_d = sum_r p[r] * V[r][h*HD+d]; write per-(block,head) partial
    float O = 0.f;
#pragma unroll
    for (int r = 0; r < RB; ++r) O = fmaf(sarr[r], smA[r * CDIM + h * HD + d], O);
    float* P = &partials[((size_t)blk * NH + h) * 34];
    P[2 + d] = O;
    if (d == 0) { P[0] = M; P[1] = S; }
}

// ---------------- kernel 3: combine online-softmax partials ----------------

__global__ __launch_bounds__(64) void combine_kernel(const float* __restrict__ partials,
                                                     float* __restrict__ attnout) {
    int bh = blockIdx.x;       // b*NH + h
    int b = bh >> 3, h = bh & 7;
    int lane = threadIdx.x;    // 64

    float M = -1e30f;
    for (int c = lane; c < CHUNKS; c += 64)
        M = fmaxf(M, partials[(((size_t)b * CHUNKS + c) * NH + h) * 34]);
#pragma unroll
    for (int m = 32; m >= 1; m >>= 1) M = fmaxf(M, __shfl_xor(M, m, 64));

    float S = 0.f;
    for (int c = lane; c < CHUNKS; c += 64) {
        const float* P = &partials[(((size_t)b * CHUNKS + c) * NH + h) * 34];
        S += P[1] * expf(P[0] - M);
    }
    S = wave_reduce_sum64(S);

    int d = lane & 31, half = lane >> 5;
    float O = 0.f;
    for (int c = half; c < CHUNKS; c += 2) {
        const float* P = &partials[(((size_t)b * CHUNKS + c) * NH + h) * 34];
        O = fmaf(P[2 + d], expf(P[0] - M), O);
    }
    O += __shfl_xor(O, 32, 64);
    if (lane < 32) attnout[b * CDIM + h * HD + d] = O / S;
}

// ---------------- kernel 4: x = attn+query; y = x + FFN(ln(x)) ----------------

__global__ __launch_bounds__(256) void epilogue_kernel(const float* __restrict__ attnout,
                                                       const float* __restrict__ query,
                                                       const float* __restrict__ gf,
                                                       const float* __restrict__ bef,
                                                       const float* __restrict__ W1,
                                                       const float* __restrict__ b1,
                                                       const float* __restrict__ W2,
                                                       const float* __restrict__ b2,
                                                       float* __restrict__ out) {
    int b = blockIdx.x;
    int tid = threadIdx.x;
    int wave = tid >> 6, lane = tid & 63;
    __shared__ float sh[FFN];
    __shared__ float red[8];

    float x = attnout[b * CDIM + tid] + query[b * CDIM + tid];
    float s = x, sq = x * x;
#pragma unroll
    for (int m = 32; m >= 1; m >>= 1) { s += __shfl_xor(s, m, 64); sq += __shfl_xor(sq, m, 64); }
    if (lane == 0) { red[wave] = s; red[4 + wave] = sq; }
    __syncthreads();
    float ts = red[0] + red[1] + red[2] + red[3];
    float tq = red[4] + red[5] + red[6] + red[7];
    float mean = ts * (1.f / CDIM);
    float var = tq * (1.f / CDIM) - mean * mean;
    float rstd = rsqrtf(var + EPS);
    sh[tid] = (x - mean) * rstd * gf[tid] + bef[tid];
    __syncthreads();

    // t1[f] = gelu(h @ W1 + b1), f = tid and tid+256
    float t[2];
#pragma unroll
    for (int i = 0; i < 2; ++i) {
        int f = tid + 256 * i;
        float a = b1[f];
        for (int k = 0; k < CDIM; ++k) a = fmaf(sh[k], W1[k * FFN + f], a);
        // exact GELU: 0.5*a*(1+erf(a/sqrt(2)))
        t[i] = 0.5f * a * (1.f + erff(a * 0.7071067811865476f));
    }
    __syncthreads();
    sh[tid] = t[0];
    sh[tid + 256] = t[1];
    __syncthreads();

    float y = b2[tid];
    for (int f = 0; f < FFN; ++f) y = fmaf(sh[f], W2[f * CDIM + tid], y);
    out[b * CDIM + tid] = x + y;
}

// ---------------- launch ----------------

extern "C" void kernel_launch(void* const* d_in, const int* in_sizes, int n_in,
                              void* d_out, int out_size, void* d_ws, size_t ws_size,
                              hipStream_t stream) {
    const float* query = (const float*)d_in[0];
    const float* mem   = (const float*)d_in[1];
    const float* ior   = (const float*)d_in[2];
    const float* Wip   = (const float*)d_in[3];
    const float* bip   = (const float*)d_in[4];
    const float* gip   = (const float*)d_in[5];
    const float* beip  = (const float*)d_in[6];
    const float* Wq    = (const float*)d_in[7];
    const float* bq    = (const float*)d_in[8];
    const float* Wkv   = (const float*)d_in[9];
    const float* bkv   = (const float*)d_in[10];
    const float* gq    = (const float*)d_in[11];
    const float* beq   = (const float*)d_in[12];
    const float* gf    = (const float*)d_in[13];
    const float* bef   = (const float*)d_in[14];
    const float* W1    = (const float*)d_in[15];
    const float* b1    = (const float*)d_in[16];
    const float* W2    = (const float*)d_in[17];
    const float* b2    = (const float*)d_in[18];
    float* out = (float*)d_out;

    float* ws = (float*)d_ws;
    float* qs       = ws;               // 16*256 = 4096 floats
    float* attnout  = ws + 4096;        // 4096 floats
    float* partials = ws + 8192;        // 8192 blocks * 8 heads * 34 = 2228224 floats (~8.9 MB)

    const int B = 16;

    qprep_kernel<<<B, 256, 0, stream>>>(query, Wq, bq, gq, beq, qs);
    main_kernel<<<B * CHUNKS, 256, 0, stream>>>(mem, Wip, bip, gip, beip, Wkv, bkv, ior, qs, partials);
    combine_kernel<<<B * NH, 64, 0, stream>>>(partials, attnout);
    epilogue_kernel<<<B, 256, 0, stream>>>(attnout, query, gf, bef, W1, b1, W2, b2, out);
}

// Round 3
// 611.335 us; speedup vs baseline: 2.9394x; 2.9394x over previous
//
#include <hip/hip_runtime.h>
#include <math.h>

#define CDIM 256
#define LDIM 16384
#define NH 8
#define HD 32
#define FFN 512
#define EPS 1e-5f
#define SCALE 0.17677669529663687f  // 1/sqrt(32)

#define RB 64              // rows per block in main kernel
#define CHUNKS (LDIM/RB)   // 256
#define LDA 264            // padded bf16 leading dim (+8 -> 2-way bank alias only)

typedef __attribute__((ext_vector_type(8))) short short8;
typedef __attribute__((ext_vector_type(4))) float f32x4;

// f32 -> bf16 (round-to-nearest-even), no header dependency
__device__ inline unsigned short f2bf(float x) {
    unsigned int u = __float_as_uint(x);
    unsigned int lsb = (u >> 16) & 1u;
    u += 0x7fffu + lsb;
    return (unsigned short)(u >> 16);
}

// ---------------- kernel 0: convert+swizzle weights to bf16 fragment layout ----------------
// wsw[((t*NC + c)*64 + l)*8 + j] = bf16(W[t*32 + (l>>4)*8 + j][c*16 + (l&15)])
// -> a wave's B-fragment load for (coltile c, k-iter t) is 1 KiB contiguous.

__global__ __launch_bounds__(256) void convert_weights(const float* __restrict__ Wip,
                                                       const float* __restrict__ Wkv,
                                                       unsigned short* __restrict__ w1,
                                                       unsigned short* __restrict__ wkv) {
    int idx = blockIdx.x * 256 + threadIdx.x;   // 131072 threads
    if (idx < 65536) {  // Wip: NC=16, 8 k-iters
        int j = idx & 7, l = (idx >> 3) & 63, c = (idx >> 9) & 15, t = idx >> 13;
        int k = t * 32 + (l >> 4) * 8 + j;
        int col = c * 16 + (l & 15);
        w1[idx] = f2bf(Wip[k * CDIM + col]);
    }
    if (idx < 131072) { // Wkv: NC=32 (K = coltiles 0..15, V = 16..31)
        int j = idx & 7, l = (idx >> 3) & 63, c = (idx >> 9) & 31, t = idx >> 14;
        int k = t * 32 + (l >> 4) * 8 + j;
        int col = c * 16 + (l & 15);
        wkv[idx] = f2bf(Wkv[k * 2 * CDIM + col]);
    }
}

// ---------------- kernel 1: q = ln(query) @ W_q + b_q, pre-scaled ----------------

__global__ __launch_bounds__(256) void qprep_kernel(const float* __restrict__ query,
                                                    const float* __restrict__ Wq,
                                                    const float* __restrict__ bq,
                                                    const float* __restrict__ gq,
                                                    const float* __restrict__ beq,
                                                    float* __restrict__ qs) {
    int b = blockIdx.x;
    int tid = threadIdx.x;
    int wave = tid >> 6, lane = tid & 63;
    __shared__ float sh[CDIM];
    __shared__ float red[8];

    float x = query[b * CDIM + tid];
    float s = x, sq = x * x;
#pragma unroll
    for (int m = 32; m >= 1; m >>= 1) { s += __shfl_xor(s, m, 64); sq += __shfl_xor(sq, m, 64); }
    if (lane == 0) { red[wave] = s; red[4 + wave] = sq; }
    __syncthreads();
    float ts = red[0] + red[1] + red[2] + red[3];
    float tq = red[4] + red[5] + red[6] + red[7];
    float mean = ts * (1.f / CDIM);
    float var = tq * (1.f / CDIM) - mean * mean;
    float rstd = rsqrtf(var + EPS);
    sh[tid] = (x - mean) * rstd * gq[tid] + beq[tid];
    __syncthreads();

    float acc = bq[tid];
    for (int k = 0; k < CDIM; ++k) acc = fmaf(sh[k], Wq[k * CDIM + tid], acc);
    qs[b * CDIM + tid] = acc * SCALE;
}

// ---------------- MFMA tile GEMM: 64x(64 per wave) from LDS-A x swizzled-global-B ----------------

__device__ inline void mfma_gemm(const unsigned short* __restrict__ smA,
                                 const unsigned short* __restrict__ wsw, int NC, int ctile0,
                                 int lx, int quad, f32x4 acc[4][4]) {
#pragma unroll
    for (int rt = 0; rt < 4; ++rt)
#pragma unroll
        for (int ci = 0; ci < 4; ++ci) acc[rt][ci] = (f32x4){0.f, 0.f, 0.f, 0.f};

    int l = quad * 16 + lx;
#pragma unroll
    for (int t = 0; t < 8; ++t) {
        short8 bfrag[4];
#pragma unroll
        for (int ci = 0; ci < 4; ++ci)
            bfrag[ci] = *(const short8*)(wsw + (((size_t)(t * NC + ctile0 + ci)) * 64 + l) * 8);
        short8 afrag[4];
#pragma unroll
        for (int rt = 0; rt < 4; ++rt)
            afrag[rt] = *(const short8*)(smA + (rt * 16 + lx) * LDA + t * 32 + quad * 8);
#pragma unroll
        for (int rt = 0; rt < 4; ++rt)
#pragma unroll
            for (int ci = 0; ci < 4; ++ci)
                acc[rt][ci] = __builtin_amdgcn_mfma_f32_16x16x32_bf16(afrag[rt], bfrag[ci], acc[rt][ci], 0, 0, 0);
    }
}

// ---------------- kernel 2: fused mem pipeline + attention partials (MFMA) ----------------
// wave w owns output coltiles 4w..4w+3 (cols 64w..64w+63) => heads 2w, 2w+1 end-to-end.
// C-fragment mapping (16x16x32): col = lane&15, row = (lane>>4)*4 + reg.

__global__ __launch_bounds__(256, 2) void main_kernel(const float* __restrict__ mem,
                                                      const unsigned short* __restrict__ w1,
                                                      const unsigned short* __restrict__ wkv,
                                                      const float* __restrict__ bip,
                                                      const float* __restrict__ gip,
                                                      const float* __restrict__ beip,
                                                      const float* __restrict__ bkv,
                                                      const float* __restrict__ ior,
                                                      const float* __restrict__ qs,
                                                      float* __restrict__ partials) {
    int blk = blockIdx.x;
    int b = blk / CHUNKS;
    int chunk = blk % CHUNKS;
    int row0 = chunk * RB;
    int tid = threadIdx.x;
    int w = tid >> 6, l = tid & 63;
    int quad = l >> 4, lx = l & 15;

    __shared__ unsigned short bufA[RB * LDA];      // 33 KiB: mem bf16, then M bf16
    __shared__ float iorS[NH][RB];                 // 2 KiB
    __shared__ float redS[4][RB];                  // 1 KiB
    __shared__ float redQ[4][RB];                  // 1 KiB
    __shared__ float stats[2][RB];                 // 0.5 KiB

    // stage ior chunk (8 heads x 64 rows)
    {
        int i0 = tid, i1 = tid + 256;
        int h0 = i0 >> 6, r0 = i0 & 63;
        int h1 = i1 >> 6, r1 = i1 & 63;
        iorS[h0][r0] = ior[((size_t)(b * NH + h0)) * LDIM + row0 + r0];
        iorS[h1][r1] = ior[((size_t)(b * NH + h1)) * LDIM + row0 + r1];
    }
    // stage mem rows -> bufA bf16 (coalesced float4 reads)
    {
        const float4* src = (const float4*)(mem + ((size_t)b * LDIM + row0) * CDIM);
#pragma unroll
        for (int it = 0; it < 16; ++it) {
            int i = tid + 256 * it;
            int r = i >> 6, c4 = i & 63;
            float4 v = src[i];
            ushort4 u;
            u.x = f2bf(v.x); u.y = f2bf(v.y); u.z = f2bf(v.z); u.w = f2bf(v.w);
            *(ushort4*)&bufA[r * LDA + c4 * 4] = u;
        }
    }
    __syncthreads();

    int col[4];
#pragma unroll
    for (int ci = 0; ci < 4; ++ci) col[ci] = (4 * w + ci) * 16 + lx;

    // ---- GEMM1: relu(mem @ Wip + bip) ----
    f32x4 acc[4][4];
    mfma_gemm(bufA, w1, 16, 4 * w, lx, quad, acc);

    float bb[4], gg[4], ee[4];
#pragma unroll
    for (int ci = 0; ci < 4; ++ci) { bb[ci] = bip[col[ci]]; gg[ci] = gip[col[ci]]; ee[ci] = beip[col[ci]]; }

    // bias+relu in-place, then per-row LN stats (wave-partial over 64 of 256 cols)
#pragma unroll
    for (int rt = 0; rt < 4; ++rt) {
#pragma unroll
        for (int reg = 0; reg < 4; ++reg) {
#pragma unroll
            for (int ci = 0; ci < 4; ++ci)
                acc[rt][ci][reg] = fmaxf(acc[rt][ci][reg] + bb[ci], 0.f);
            float s = acc[rt][0][reg] + acc[rt][1][reg] + acc[rt][2][reg] + acc[rt][3][reg];
            float q = acc[rt][0][reg] * acc[rt][0][reg] + acc[rt][1][reg] * acc[rt][1][reg]
                    + acc[rt][2][reg] * acc[rt][2][reg] + acc[rt][3][reg] * acc[rt][3][reg];
#pragma unroll
            for (int m = 8; m >= 1; m >>= 1) { s += __shfl_xor(s, m, 64); q += __shfl_xor(q, m, 64); }
            if (lx == 0) {
                int row = rt * 16 + quad * 4 + reg;
                redS[w][row] = s;
                redQ[w][row] = q;
            }
        }
    }
    __syncthreads();   // also guarantees all GEMM1 reads of bufA are done
    if (tid < RB) {
        float s = redS[0][tid] + redS[1][tid] + redS[2][tid] + redS[3][tid];
        float q = redQ[0][tid] + redQ[1][tid] + redQ[2][tid] + redQ[3][tid];
        float mean = s * (1.f / CDIM);
        float var = q * (1.f / CDIM) - mean * mean;
        stats[0][tid] = mean;
        stats[1][tid] = rsqrtf(var + EPS);
    }
    __syncthreads();

    // LN -> bf16 M, overwrite bufA
#pragma unroll
    for (int rt = 0; rt < 4; ++rt)
#pragma unroll
        for (int reg = 0; reg < 4; ++reg) {
            int row = rt * 16 + quad * 4 + reg;
            float mean = stats[0][row], rstd = stats[1][row];
#pragma unroll
            for (int ci = 0; ci < 4; ++ci) {
                float y = (acc[rt][ci][reg] - mean) * rstd * gg[ci] + ee[ci];
                bufA[row * LDA + col[ci]] = f2bf(y);
            }
        }
    __syncthreads();

    // ---- K = M @ Wkv[:, :256] + bkv ----
    f32x4 acc2[4][4];
    mfma_gemm(bufA, wkv, 32, 4 * w, lx, quad, acc2);

    // scores for heads h0=2w (ci 0,1), h1=2w+1 (ci 2,3)
    float qv[4], bk[4];
#pragma unroll
    for (int ci = 0; ci < 4; ++ci) { qv[ci] = qs[b * CDIM + col[ci]]; bk[ci] = bkv[col[ci]]; }

    float p0[16], p1[16];
    float M0 = -1e30f, M1 = -1e30f;
#pragma unroll
    for (int rt = 0; rt < 4; ++rt)
#pragma unroll
        for (int reg = 0; reg < 4; ++reg) {
            float s0 = (acc2[rt][0][reg] + bk[0]) * qv[0] + (acc2[rt][1][reg] + bk[1]) * qv[1];
            float s1 = (acc2[rt][2][reg] + bk[2]) * qv[2] + (acc2[rt][3][reg] + bk[3]) * qv[3];
#pragma unroll
            for (int m = 8; m >= 1; m >>= 1) { s0 += __shfl_xor(s0, m, 64); s1 += __shfl_xor(s1, m, 64); }
            int row = rt * 16 + quad * 4 + reg;
            s0 *= iorS[2 * w][row];
            s1 *= iorS[2 * w + 1][row];
            p0[rt * 4 + reg] = s0;
            p1[rt * 4 + reg] = s1;
            M0 = fmaxf(M0, s0);
            M1 = fmaxf(M1, s1);
        }
    M0 = fmaxf(M0, __shfl_xor(M0, 16, 64)); M0 = fmaxf(M0, __shfl_xor(M0, 32, 64));
    M1 = fmaxf(M1, __shfl_xor(M1, 16, 64)); M1 = fmaxf(M1, __shfl_xor(M1, 32, 64));
    float S0 = 0.f, S1 = 0.f;
#pragma unroll
    for (int i = 0; i < 16; ++i) {
        p0[i] = __expf(p0[i] - M0); S0 += p0[i];
        p1[i] = __expf(p1[i] - M1); S1 += p1[i];
    }
    S0 += __shfl_xor(S0, 16, 64); S0 += __shfl_xor(S0, 32, 64);
    S1 += __shfl_xor(S1, 16, 64); S1 += __shfl_xor(S1, 32, 64);

    // ---- V = M @ Wkv[:, 256:] + bkv[256:] ----
    f32x4 acc3[4][4];
    mfma_gemm(bufA, wkv, 32, 16 + 4 * w, lx, quad, acc3);

    // O_d = sum_r p[r] * V[r][d] (reduce over quads via shfl)
    float o[4];
#pragma unroll
    for (int ci = 0; ci < 4; ++ci) {
        float bo = bkv[CDIM + col[ci]];
        const float* pp = (ci < 2) ? p0 : p1;
        float a = 0.f;
#pragma unroll
        for (int rt = 0; rt < 4; ++rt)
#pragma unroll
            for (int reg = 0; reg < 4; ++reg)
                a = fmaf(pp[rt * 4 + reg], acc3[rt][ci][reg] + bo, a);
        a += __shfl_xor(a, 16, 64);
        a += __shfl_xor(a, 32, 64);
        o[ci] = a;
    }

    float* P0 = &partials[((size_t)blk * NH + 2 * w) * 34];
    float* P1 = P0 + 34;
    if (quad == 0) {
        P0[2 + lx] = o[0];
        P0[2 + 16 + lx] = o[1];
        P1[2 + lx] = o[2];
        P1[2 + 16 + lx] = o[3];
        if (lx == 0) { P0[0] = M0; P0[1] = S0; P1[0] = M1; P1[1] = S1; }
    }
}

// ---------------- kernel 3: combine online-softmax partials ----------------

__global__ __launch_bounds__(64) void combine_kernel(const float* __restrict__ partials,
                                                     float* __restrict__ attnout) {
    int bh = blockIdx.x;       // b*NH + h
    int b = bh >> 3, h = bh & 7;
    int lane = threadIdx.x;    // 64

    float M = -1e30f;
    for (int c = lane; c < CHUNKS; c += 64)
        M = fmaxf(M, partials[(((size_t)b * CHUNKS + c) * NH + h) * 34]);
#pragma unroll
    for (int m = 32; m >= 1; m >>= 1) M = fmaxf(M, __shfl_xor(M, m, 64));

    float S = 0.f;
    for (int c = lane; c < CHUNKS; c += 64) {
        const float* P = &partials[(((size_t)b * CHUNKS + c) * NH + h) * 34];
        S += P[1] * __expf(P[0] - M);
    }
#pragma unroll
    for (int m = 32; m >= 1; m >>= 1) S += __shfl_xor(S, m, 64);

    int d = lane & 31, half = lane >> 5;
    float O = 0.f;
    for (int c = half; c < CHUNKS; c += 2) {
        const float* P = &partials[(((size_t)b * CHUNKS + c) * NH + h) * 34];
        O = fmaf(P[2 + d], __expf(P[0] - M), O);
    }
    O += __shfl_xor(O, 32, 64);
    if (lane < 32) attnout[b * CDIM + h * HD + d] = O / S;
}

// ---------------- kernel 4: x = attn+query; y = x + FFN(ln(x)) ----------------

__global__ __launch_bounds__(256) void epilogue_kernel(const float* __restrict__ attnout,
                                                       const float* __restrict__ query,
                                                       const float* __restrict__ gf,
                                                       const float* __restrict__ bef,
                                                       const float* __restrict__ W1,
                                                       const float* __restrict__ b1,
                                                       const float* __restrict__ W2,
                                                       const float* __restrict__ b2,
                                                       float* __restrict__ out) {
    int b = blockIdx.x;
    int tid = threadIdx.x;
    int wave = tid >> 6, lane = tid & 63;
    __shared__ float sh[FFN];
    __shared__ float red[8];

    float x = attnout[b * CDIM + tid] + query[b * CDIM + tid];
    float s = x, sq = x * x;
#pragma unroll
    for (int m = 32; m >= 1; m >>= 1) { s += __shfl_xor(s, m, 64); sq += __shfl_xor(sq, m, 64); }
    if (lane == 0) { red[wave] = s; red[4 + wave] = sq; }
    __syncthreads();
    float ts = red[0] + red[1] + red[2] + red[3];
    float tq = red[4] + red[5] + red[6] + red[7];
    float mean = ts * (1.f / CDIM);
    float var = tq * (1.f / CDIM) - mean * mean;
    float rstd = rsqrtf(var + EPS);
    sh[tid] = (x - mean) * rstd * gf[tid] + bef[tid];
    __syncthreads();

    float t[2];
#pragma unroll
    for (int i = 0; i < 2; ++i) {
        int f = tid + 256 * i;
        float a = b1[f];
        for (int k = 0; k < CDIM; ++k) a = fmaf(sh[k], W1[k * FFN + f], a);
        t[i] = 0.5f * a * (1.f + erff(a * 0.7071067811865476f));
    }
    __syncthreads();
    sh[tid] = t[0];
    sh[tid + 256] = t[1];
    __syncthreads();

    float y = b2[tid];
    for (int f = 0; f < FFN; ++f) y = fmaf(sh[f], W2[f * CDIM + tid], y);
    out[b * CDIM + tid] = x + y;
}

// ---------------- launch ----------------

extern "C" void kernel_launch(void* const* d_in, const int* in_sizes, int n_in,
                              void* d_out, int out_size, void* d_ws, size_t ws_size,
                              hipStream_t stream) {
    const float* query = (const float*)d_in[0];
    const float* mem   = (const float*)d_in[1];
    const float* ior   = (const float*)d_in[2];
    const float* Wip   = (const float*)d_in[3];
    const float* bip   = (const float*)d_in[4];
    const float* gip   = (const float*)d_in[5];
    const float* beip  = (const float*)d_in[6];
    const float* Wq    = (const float*)d_in[7];
    const float* bq    = (const float*)d_in[8];
    const float* Wkv   = (const float*)d_in[9];
    const float* bkv   = (const float*)d_in[10];
    const float* gq    = (const float*)d_in[11];
    const float* beq   = (const float*)d_in[12];
    const float* gf    = (const float*)d_in[13];
    const float* bef   = (const float*)d_in[14];
    const float* W1    = (const float*)d_in[15];
    const float* b1    = (const float*)d_in[16];
    const float* W2    = (const float*)d_in[17];
    const float* b2    = (const float*)d_in[18];
    float* out = (float*)d_out;

    char* ws = (char*)d_ws;
    float* qs             = (float*)(ws);                       // 16384 B
    float* attnout        = (float*)(ws + 16384);               // 16384 B
    float* partials       = (float*)(ws + 32768);               // 4096*8*34*4 = 4456448 B
    unsigned short* w1sw  = (unsigned short*)(ws + 32768 + 4456448);            // 131072 B
    unsigned short* wkvsw = (unsigned short*)(ws + 32768 + 4456448 + 131072);   // 262144 B

    const int B = 16;

    convert_weights<<<512, 256, 0, stream>>>(Wip, Wkv, w1sw, wkvsw);
    qprep_kernel<<<B, 256, 0, stream>>>(query, Wq, bq, gq, beq, qs);
    main_kernel<<<B * CHUNKS, 256, 0, stream>>>(mem, w1sw, wkvsw, bip, gip, beip, bkv, ior, qs, partials);
    combine_kernel<<<B * NH, 64, 0, stream>>>(partials, attnout);
    epilogue_kernel<<<B, 256, 0, stream>>>(attnout, query, gf, bef, W1, b1, W2, b2, out);
}